// Round 14
// baseline (830.881 us; speedup 1.0000x reference)
//
#include <hip/hip_runtime.h>
#include <hip/hip_bf16.h>
#include <math.h>

#define BDIM 16384
#define HDIM 512

typedef __bf16 bf16;
typedef float f32x4 __attribute__((ext_vector_type(4)));
typedef __bf16 bf16x8 __attribute__((ext_vector_type(8)));
typedef __bf16 bf16x4 __attribute__((ext_vector_type(4)));

#define WAITV(N) asm volatile("s_waitcnt vmcnt(" #N ")" ::: "memory")

// ---------------------------------------------------------------- utilities

__device__ __forceinline__ void gload16(const bf16* g, bf16* l) {
  __builtin_amdgcn_global_load_lds((const __attribute__((address_space(1))) void*)g,
                                   (__attribute__((address_space(3))) void*)l, 16, 0, 0);
}

__device__ __forceinline__ float gelu_exact(float x) {
  return 0.5f * x * (1.0f + erff(x * 0.70710678118654752f));
}
// gelu(x) ~= x * sigmoid(1.5957692*(x + 0.044715 x^3)); exp2-form, fast rcp.
__device__ __forceinline__ float gelu_fast2(float x) {
  float x3 = x * x * x;
  float e = exp2f(fmaf(-0.1029432f, x3, -2.3022082f * x));
  return x * __builtin_amdgcn_rcpf(1.f + e);
}

// ---------------------------------------------------------------- converts

__global__ void cvt_f32_bf16(const float* __restrict__ src, bf16* __restrict__ dst, int n4) {
  int i = blockIdx.x * blockDim.x + threadIdx.x;
  if (i >= n4) return;
  f32x4 v = *(const f32x4*)(src + (size_t)i * 4);
  bf16x4 o;
  o[0] = (bf16)v[0]; o[1] = (bf16)v[1]; o[2] = (bf16)v[2]; o[3] = (bf16)v[3];
  *(bf16x4*)(dst + (size_t)i * 4) = o;
}

// wvT[il][k][m] = wv[il][m][k]; wv = rows 1024..1535 of qkv block il ([1536][512])
__global__ void cvt_wvT(const float* __restrict__ qkv, bf16* __restrict__ dst) {
  __shared__ float t[32][33];
  int il = blockIdx.z;
  int bm = blockIdx.x * 32;
  int bk = blockIdx.y * 32;
  const float* s = qkv + (size_t)il * 786432 + 524288;
  int tx = threadIdx.x & 31, ty = threadIdx.x >> 5;
#pragma unroll
  for (int j = 0; j < 4; ++j)
    t[ty * 4 + j][tx] = s[(size_t)(bm + ty * 4 + j) * 512 + bk + tx];
  __syncthreads();
  bf16* d = dst + (size_t)il * 262144;
#pragma unroll
  for (int j = 0; j < 4; ++j)
    d[(size_t)(bk + ty * 4 + j) * 512 + bm + tx] = (bf16)t[tx][ty * 4 + j];
}

__global__ void zfill(float* __restrict__ p, int n) {
  int i = blockIdx.x * 256 + threadIdx.x;
  if (i < n) p[i] = 0.f;
}

// bc[il][n] = sum_m ao[il][n][m] * bv[il][m] + aob[il][n]
__global__ void bias_combine(const float* __restrict__ aow, const float* __restrict__ qkvb,
                             const float* __restrict__ aob, float* __restrict__ bc) {
  int gid = blockIdx.x * 4 + (threadIdx.x >> 6);
  int il = gid >> 9;
  int lane = threadIdx.x & 63;
  const float* ar = aow + (size_t)gid * 512 + lane * 8;
  const float* bv = qkvb + il * 1536 + 1024 + lane * 8;
  float s = 0.f;
#pragma unroll
  for (int i = 0; i < 8; ++i) s += ar[i] * bv[i];
#pragma unroll
  for (int off = 32; off > 0; off >>= 1) s += __shfl_xor(s, off);
  if (lane == 0) bc[gid] = s + aob[gid];
}

// ---------------------------------------------------------------- gemm_8p (all big GEMMs)
// 256x256 tile, BK=64, 8 waves (2Mx4N), 128 KiB LDS: 2 bufs x 4 regions
// {A-kh0, A-kh1, B-kh0, B-kh1} of [256 rows][32]. 8-phase schedule with
// READ-AHEAD: each phase's ds_reads are issued in the PREVIOUS phase (after
// its MFMA, before its end barrier), so post-barrier only lgkm+MFMA remain.
// vmcnt(6) at every phase; full stage->read/overwrite ledger hand-checked.
// Swapped mfma(b,a); both-sides swizzle identical to prior verified kernels.

template<int ACT, bool RES, int K>
__launch_bounds__(512, 1)
__global__ void gemm_8p(const bf16* __restrict__ A, long long Az,
                        const bf16* __restrict__ W, long long Wz,
                        const float* __restrict__ bias, long long bz,
                        const bf16* X, long long Xz,
                        bf16* C, long long Cz, int ldc) {
  __shared__ bf16 lds[65536];   // 128 KiB
  const long long z = blockIdx.z;
  A += z * Az; W += z * Wz; bias += z * bz; C += z * Cz;
  if (RES) X += z * Xz;
  const int tid = threadIdx.x, lane = tid & 63, wid = tid >> 6;
  const int brow = blockIdx.x * 256, bcol = blockIdx.y * 256;
  const int wm = (wid >> 2) * 128;   // 2 M-groups
  const int wn = (wid & 3) * 64;     // 4 N-groups
  const int lr = lane & 15, kg = lane >> 4;
  const int ko = (kg ^ ((lr >> 1) & 3)) << 3;

  f32x4 acc[8][4] = {};

  // staging: one region (256x32) = 2 gload16 calls (128 rows each).
  const int sco = (((tid & 3) ^ ((tid >> 3) & 3)) << 3);
  const bf16* Ag = A + (size_t)(brow + (tid >> 2)) * K + sco;
  const bf16* Wg = W + (size_t)(bcol + (tid >> 2)) * K + sco;
  const int nt = K / 64;

  auto STG = [&](const bf16* gbase, int kt, int kh, int dstE) {
    int ck = kt < nt ? kt : nt - 1;   // dummy-clamp keeps vmcnt ledger uniform
    const bf16* s = gbase + (size_t)ck * 64 + (size_t)kh * 32;
    gload16(s, lds + dstE + wid * 512);
    gload16(s + (size_t)128 * K, lds + dstE + 4096 + wid * 512);
  };
  // region bases (elems): buf*32768 + {A0:0, A1:8192, B0:16384, B1:24576}

  // prologue stages (ledger order): (0)A0,(0)B0,(0)A1,(0)B1,(1)A0,(1)B0
  STG(Ag, 0, 0, 0);          STG(Wg, 0, 0, 16384);
  STG(Ag, 0, 1, 8192);       STG(Wg, 0, 1, 24576);
  STG(Ag, 1, 0, 32768);      STG(Wg, 1, 0, 32768 + 16384);

  bf16x8 a[8], b01[2], b23[2];

#define RD_A(BASE)                                                             \
  { _Pragma("unroll") for (int m = 0; m < 8; ++m)                              \
      a[m] = *(const bf16x8*)(lds + (BASE) + ((wm + m * 16 + lr) << 5) + ko); }
#define RD_B01(BASE)                                                           \
  { b01[0] = *(const bf16x8*)(lds + (BASE) + ((wn + lr) << 5) + ko);           \
    b01[1] = *(const bf16x8*)(lds + (BASE) + ((wn + 16 + lr) << 5) + ko); }
#define RD_B23(BASE)                                                           \
  { b23[0] = *(const bf16x8*)(lds + (BASE) + ((wn + 32 + lr) << 5) + ko);      \
    b23[1] = *(const bf16x8*)(lds + (BASE) + ((wn + 48 + lr) << 5) + ko); }
#define MM(N0, BB)                                                             \
  { __builtin_amdgcn_s_setprio(1);                                             \
    _Pragma("unroll") for (int m = 0; m < 8; ++m) {                            \
      acc[m][N0]     = __builtin_amdgcn_mfma_f32_16x16x32_bf16(BB[0], a[m], acc[m][N0], 0, 0, 0);     \
      acc[m][N0 + 1] = __builtin_amdgcn_mfma_f32_16x16x32_bf16(BB[1], a[m], acc[m][N0 + 1], 0, 0, 0); } \
    __builtin_amdgcn_s_setprio(0); }
#define BARW                                                                   \
  WAITV(6); __builtin_amdgcn_s_barrier(); asm volatile("" ::: "memory");
#define ENDP                                                                   \
  asm volatile("" ::: "memory"); __builtin_amdgcn_s_barrier();

  // pre-loop: retire (0)A0,(0)B0 (vmcnt(6) over 12 issued), read phase-0 regs
  BARW
  RD_A(0) RD_B01(16384)

  const int niter = nt / 2;
  for (int i = 0; i < niter; ++i) {
    const int t = 2 * i;
    // ph0 (buf0 kh0 n01)
    STG(Ag, t + 1, 1, 32768 + 8192);
    BARW  MM(0, b01)  RD_B23(16384)                      ENDP
    // ph1 (buf0 kh0 n23)
    STG(Wg, t + 1, 1, 32768 + 24576);
    BARW  MM(2, b23)  RD_A(8192) RD_B01(24576)           ENDP
    // ph2 (buf0 kh1 n01)
    STG(Ag, t + 2, 0, 0);
    BARW  MM(0, b01)  RD_B23(24576)                      ENDP
    // ph3 (buf0 kh1 n23)
    STG(Wg, t + 2, 0, 16384);
    BARW  MM(2, b23)  RD_A(32768) RD_B01(49152)          ENDP
    // ph4 (buf1 kh0 n01)
    STG(Ag, t + 2, 1, 8192);
    BARW  MM(0, b01)  RD_B23(49152)                      ENDP
    // ph5 (buf1 kh0 n23)
    STG(Wg, t + 2, 1, 24576);
    BARW  MM(2, b23)  RD_A(40960) RD_B01(57344)          ENDP
    // ph6 (buf1 kh1 n01)
    STG(Ag, t + 3, 0, 32768);
    BARW  MM(0, b01)  RD_B23(57344)                      ENDP
    // ph7 (buf1 kh1 n23)
    STG(Wg, t + 3, 0, 32768 + 16384);
    BARW  MM(2, b23)  RD_A(0) RD_B01(16384)              ENDP
  }
#undef RD_A
#undef RD_B01
#undef RD_B23
#undef MM
#undef BARW
#undef ENDP

  // epilogue (swapped D): row = brow+wm+m*16+lr; cols = bcol+wn+n*16+kg*4 .. +3
  f32x4 bv4[4];
#pragma unroll
  for (int n = 0; n < 4; ++n)
    bv4[n] = *(const f32x4*)(bias + bcol + wn + n * 16 + kg * 4);
#pragma unroll
  for (int m = 0; m < 8; ++m) {
    int row = brow + wm + m * 16 + lr;
#pragma unroll
    for (int n = 0; n < 4; ++n) {
      int col = bcol + wn + n * 16 + kg * 4;
      f32x4 v;
#pragma unroll
      for (int j = 0; j < 4; ++j) {
        float t2 = acc[m][n][j] + bv4[n][j];
        if (ACT == 1) t2 = gelu_fast2(t2);
        v[j] = t2;
      }
      if (RES) {
        bf16x4 xv = *(const bf16x4*)(X + (size_t)row * 512 + col);
#pragma unroll
        for (int j = 0; j < 4; ++j) v[j] += (float)xv[j];
      }
      bf16x4 o;
#pragma unroll
      for (int j = 0; j < 4; ++j) o[j] = (bf16)v[j];
      *(bf16x4*)(C + (size_t)row * ldc + col) = o;
    }
  }
}

// ---------------------------------------------------------------- ln_chain
// MODE 0: O = LN_A(Y);  MODE 1: O = LN_B( LN_A(Y) + R )

template<int MODE>
__global__ void ln_chain(const bf16* __restrict__ Y, const bf16* __restrict__ R,
                         const float* __restrict__ gA, const float* __restrict__ bA,
                         const float* __restrict__ gB, const float* __restrict__ bB,
                         bf16* __restrict__ O) {
  int lane = threadIdx.x & 63;
  int row = blockIdx.x * 4 + (threadIdx.x >> 6);
  int gen = row >> 14;
  size_t base = (size_t)row * HDIM + lane * 8;
  bf16x8 yv = *(const bf16x8*)(Y + base);
  float v[8], s = 0.f, q = 0.f;
#pragma unroll
  for (int i = 0; i < 8; ++i) { v[i] = (float)yv[i]; s += v[i]; q += v[i] * v[i]; }
#pragma unroll
  for (int off = 32; off > 0; off >>= 1) { s += __shfl_xor(s, off); q += __shfl_xor(q, off); }
  float mean = s * (1.f / HDIM);
  float rstd = rsqrtf(q * (1.f / HDIM) - mean * mean + 1e-5f);
  const float* gAp = gA + gen * 1536 + lane * 8;
  const float* bAp = bA + gen * 1536 + lane * 8;
  if (MODE == 0) {
    bf16x8 o;
#pragma unroll
    for (int i = 0; i < 8; ++i) o[i] = (bf16)((v[i] - mean) * rstd * gAp[i] + bAp[i]);
    *(bf16x8*)(O + base) = o;
    return;
  }
  bf16x8 rv = *(const bf16x8*)(R + base);
  float u[8]; s = 0.f; q = 0.f;
#pragma unroll
  for (int i = 0; i < 8; ++i) {
    u[i] = (v[i] - mean) * rstd * gAp[i] + bAp[i] + (float)rv[i];
    s += u[i]; q += u[i] * u[i];
  }
#pragma unroll
  for (int off = 32; off > 0; off >>= 1) { s += __shfl_xor(s, off); q += __shfl_xor(q, off); }
  float m2 = s * (1.f / HDIM);
  float r2 = rsqrtf(q * (1.f / HDIM) - m2 * m2 + 1e-5f);
  const float* gBp = gB + gen * 1536 + lane * 8;
  const float* bBp = bB + gen * 1536 + lane * 8;
  bf16x8 o;
#pragma unroll
  for (int i = 0; i < 8; ++i) o[i] = (bf16)((u[i] - m2) * r2 * gBp[i] + bBp[i]);
  *(bf16x8*)(O + base) = o;
}

// ---------------------------------------------------------------- GEMM 128x128 (tiny: Wc)

__launch_bounds__(256)
__global__ void gemm128(const bf16* __restrict__ A, long long Az, int lda,
                        const bf16* __restrict__ W, long long Wz,
                        const float* __restrict__ bias, long long bz,
                        bf16* __restrict__ C, long long Cz, int ldc, int K) {
  __shared__ bf16 As[128 * 64];
  __shared__ bf16 Bs[128 * 64];
  const long long z = blockIdx.z;
  A += z * Az; W += z * Wz; bias += z * bz; C += z * Cz;
  const int tid = threadIdx.x;
  const int lane = tid & 63;
  const int wid = tid >> 6;
  const int brow = blockIdx.x * 128;
  const int bcol = blockIdx.y * 128;
  const int wr = (wid >> 1) * 64;
  const int wc = (wid & 1) * 64;
  const int lr = lane & 15;
  const int kg = lane >> 4;
  f32x4 acc[4][4] = {};
  const bf16* Abase = A + (size_t)(brow + (tid >> 3)) * lda + ((tid & 7) << 3);
  const bf16* Wbase = W + (size_t)(bcol + (tid >> 3)) * K + ((tid & 7) << 3);
  bf16* AsDst = As + wid * 512;
  bf16* BsDst = Bs + wid * 512;
  for (int k0 = 0; k0 < K; k0 += 64) {
#pragma unroll
    for (int j = 0; j < 4; ++j) {
      gload16(Abase + (size_t)j * 32 * lda + k0, AsDst + j * 2048);
      gload16(Wbase + (size_t)j * 32 * K + k0, BsDst + j * 2048);
    }
    __syncthreads();
#pragma unroll
    for (int kk = 0; kk < 64; kk += 32) {
      bf16x8 a[4], bq[4];
#pragma unroll
      for (int m = 0; m < 4; ++m)
        a[m] = *(const bf16x8*)(As + (wr + m * 16 + lr) * 64 + kk + kg * 8);
#pragma unroll
      for (int n = 0; n < 4; ++n)
        bq[n] = *(const bf16x8*)(Bs + (wc + n * 16 + lr) * 64 + kk + kg * 8);
#pragma unroll
      for (int m = 0; m < 4; ++m)
#pragma unroll
        for (int n = 0; n < 4; ++n)
          acc[m][n] = __builtin_amdgcn_mfma_f32_16x16x32_bf16(a[m], bq[n], acc[m][n], 0, 0, 0);
    }
    __syncthreads();
  }
  float bv[4];
#pragma unroll
  for (int n = 0; n < 4; ++n) bv[n] = bias[bcol + wc + n * 16 + lr];
#pragma unroll
  for (int m = 0; m < 4; ++m) {
    int row = brow + wr + m * 16 + kg * 4;
#pragma unroll
    for (int n = 0; n < 4; ++n) {
      int col = bcol + wc + n * 16 + lr;
#pragma unroll
      for (int j = 0; j < 4; ++j)
        C[(size_t)(row + j) * ldc + col] = (bf16)(acc[m][n][j] + bv[n]);
    }
  }
}

// ---------------------------------------------------------------- prior MLP (tiny)

__global__ void prior_fc1(const float* __restrict__ emb, const float* __restrict__ w1,
                          const float* __restrict__ b1, float* __restrict__ h) {
  int j = blockIdx.x * 4 + (threadIdx.x >> 6);
  int lane = threadIdx.x & 63;
  const float* wr = w1 + (size_t)j * 512 + lane * 8;
  const float* e = emb + lane * 8;
  float s = 0.f;
#pragma unroll
  for (int i = 0; i < 8; ++i) s += e[i] * wr[i];
#pragma unroll
  for (int off = 32; off > 0; off >>= 1) s += __shfl_xor(s, off);
  if (lane == 0) h[j] = gelu_exact(s + b1[j]);
}

__global__ void prior_fc2(const float* __restrict__ h, const float* __restrict__ w2,
                          const float* __restrict__ b2, float* __restrict__ p) {
  int j = blockIdx.x * 4 + (threadIdx.x >> 6);
  int lane = threadIdx.x & 63;
  const float* wr = w2 + (size_t)j * 1024 + lane * 16;
  const float* e = h + lane * 16;
  float s = 0.f;
#pragma unroll
  for (int i = 0; i < 16; ++i) s += e[i] * wr[i];
#pragma unroll
  for (int off = 32; off > 0; off >>= 1) s += __shfl_xor(s, off);
  if (lane == 0) p[j] = s + b2[j];
}

// ---------------------------------------------------------------- final select/blend

__global__ void combine(const float* __restrict__ img, const float* __restrict__ txt,
                        const bf16* __restrict__ gen_t, const bf16* __restrict__ gen_i,
                        const float* __restrict__ prior, const int* __restrict__ mt,
                        const float* __restrict__ rw, float* __restrict__ out) {
  int i4 = blockIdx.x * blockDim.x + threadIdx.x;
  if (i4 >= BDIM * 128) return;
  int bb = i4 >> 7;
  int c = (i4 & 127) << 2;
  size_t idx = (size_t)bb * HDIM + c;
  int m = mt[bb];
  f32x4 iv = *(const f32x4*)(img + idx);
  f32x4 tv = *(const f32x4*)(txt + idx);
  f32x4 oi = iv, ot = tv;
  if (m == 2) {
    float r = rw[1];
    bf16x4 gv = *(const bf16x4*)(gen_i + idx);
#pragma unroll
    for (int k = 0; k < 4; ++k) oi[k] = r * iv[k] + (1.f - r) * (float)gv[k];
  } else if (m == 3) {
    oi = *(const f32x4*)(prior + c);
  }
  if (m == 1) {
    float r = rw[0];
    bf16x4 gv = *(const bf16x4*)(gen_t + idx);
#pragma unroll
    for (int k = 0; k < 4; ++k) ot[k] = r * tv[k] + (1.f - r) * (float)gv[k];
  } else if (m == 3) {
    ot = *(const f32x4*)(prior + 512 + c);
  }
  *(f32x4*)(out + idx) = oi;
  *(f32x4*)(out + (size_t)BDIM * HDIM + idx) = ot;
}

// ---------------------------------------------------------------- launch

extern "C" void kernel_launch(void* const* d_in, const int* in_sizes, int n_in,
                              void* d_out, int out_size, void* d_ws, size_t ws_size,
                              hipStream_t stream) {
  const float* img  = (const float*)d_in[0];
  const float* txt  = (const float*)d_in[1];
  const float* ipw  = (const float*)d_in[2];
  const float* ipb  = (const float*)d_in[3];
  const float* qkvw = (const float*)d_in[4];
  const float* qkvb = (const float*)d_in[5];
  const float* aow  = (const float*)d_in[6];
  const float* aob  = (const float*)d_in[7];
  const float* ln1g = (const float*)d_in[8];
  const float* ln1b = (const float*)d_in[9];
  const float* ln2g = (const float*)d_in[10];
  const float* ln2b = (const float*)d_in[11];
  const float* f1w  = (const float*)d_in[12];
  const float* f1b  = (const float*)d_in[13];
  const float* f2w  = (const float*)d_in[14];
  const float* f2b  = (const float*)d_in[15];
  const float* opw  = (const float*)d_in[16];
  const float* opb  = (const float*)d_in[17];
  const float* rw   = (const float*)d_in[18];
  const float* pw1  = (const float*)d_in[19];
  const float* pb1  = (const float*)d_in[20];
  const float* pw2  = (const float*)d_in[21];
  const float* pb2  = (const float*)d_in[22];
  const float* pemb = (const float*)d_in[23];
  const int*   mt   = (const int*)d_in[24];
  float* out = (float*)d_out;

  const size_t B = BDIM;
  char* ws = (char*)d_ws;
  size_t off = 0;
  auto alloc = [&](size_t bytes) -> char* {
    char* p = ws + off;
    off += (bytes + 255) & ~(size_t)255;
    return p;
  };
  bf16* src_bf = (bf16*)alloc(2 * B * 512 * 2);           // [0]=img, [1]=txt
  bf16* ipw_bf = (bf16*)alloc((size_t)2 * 262144 * 2);
  bf16* wvT_bf = (bf16*)alloc((size_t)6 * 262144 * 2);
  bf16* ao_bf  = (bf16*)alloc((size_t)6 * 262144 * 2);
  bf16* f1_bf  = (bf16*)alloc((size_t)6 * 1048576 * 2);
  bf16* f2_bf  = (bf16*)alloc((size_t)6 * 1048576 * 2);
  bf16* op_bf  = (bf16*)alloc((size_t)2 * 262144 * 2);
  bf16* Wc_bf  = (bf16*)alloc((size_t)6 * 262144 * 2);
  float* bc    = (float*)alloc(6 * 512 * 4);
  float* zeros = (float*)alloc(512 * 4);
  float* ph    = (float*)alloc(1024 * 4);
  float* pout  = (float*)alloc(1024 * 4);
  bf16* xn     = (bf16*)alloc(2 * B * 512 * 2);
  bf16* hreg   = (bf16*)alloc((size_t)B * 2048 * 2);   // 64 MB: gen1 h / attn buf / gen buf
  bf16* h0     = (bf16*)d_out;                          // 64 MB: gen0 h (dead before combine)
  const long long HZ = (long long)(hreg - h0);          // z-stride h0 -> h1

  auto cvt = [&](const float* s, bf16* d, size_t n) {
    int n4 = (int)(n / 4);
    cvt_f32_bf16<<<(n4 + 255) / 256, 256, 0, stream>>>(s, d, n4);
  };
  cvt(img, src_bf, B * 512);
  cvt(txt, src_bf + B * 512, B * 512);
  cvt(ipw, ipw_bf, 2 * 262144);
  cvt(aow, ao_bf, 6 * 262144);
  cvt(f1w, f1_bf, 6 * 1048576);
  cvt(f2w, f2_bf, 6 * 1048576);
  cvt(opw, op_bf, 2 * 262144);
  cvt_wvT<<<dim3(16, 16, 6), 256, 0, stream>>>(qkvw, wvT_bf);
  zfill<<<2, 256, 0, stream>>>(zeros, 512);
  bias_combine<<<768, 256, 0, stream>>>(aow, qkvb, aob, bc);
  gemm128<<<dim3(4, 4, 6), 256, 0, stream>>>(ao_bf, 262144, 512, wvT_bf, 262144,
                                             zeros, 0, Wc_bf, 262144, 512, 512);
  prior_fc1<<<256, 256, 0, stream>>>(pemb, pw1, pb1, ph);
  prior_fc2<<<256, 256, 0, stream>>>(ph, pw2, pb2, pout);

  const long long BS = (long long)B * 512;

  // attn_l -> hreg (z=0) / hreg+BS (z=1); tgt: z=0 -> txt, z=1 -> img
  auto attn = [&](int l) {
    gemm_8p<0, false, 512><<<dim3(64, 2, 2), 512, 0, stream>>>(
        src_bf + BS, -BS, Wc_bf + (size_t)l * 262144, 786432,
        bc + l * 512, 1536, nullptr, 0, hreg, BS, 512);
  };

  // xn = src@ipw^T + ipb + attn0;  xn = LN1_0(xn)
  attn(0);
  gemm_8p<0, true, 512><<<dim3(64, 2, 2), 512, 0, stream>>>(
      src_bf, BS, ipw_bf, 262144, ipb, 512, hreg, BS, xn, BS, 512);
  ln_chain<0><<<2 * BDIM / 4, 256, 0, stream>>>(xn, nullptr, ln1g, ln1b,
                                                nullptr, nullptr, xn);

  for (int l = 0; l < 3; ++l) {
    // h = gelu(xn @ f1^T + b1)   (z-batched: gen0 h in d_out, gen1 in hreg)
    gemm_8p<1, false, 512><<<dim3(64, 8, 2), 512, 0, stream>>>(
        xn, BS, f1_bf + (size_t)l * 1048576, 3145728,
        f1b + l * 2048, 6144, nullptr, 0, h0, HZ, 2048);
    // xn = xn + h @ f2^T + b2   (z-batched, in place)
    gemm_8p<0, true, 2048><<<dim3(64, 2, 2), 512, 0, stream>>>(
        h0, HZ, f2_bf + (size_t)l * 1048576, 3145728,
        f2b + l * 512, 1536, xn, BS, xn, BS, 512);
    if (l < 2) {
      attn(l + 1);   // h dead now; hreg reused as attn buffer
      // xn = LN1_{l+1}( LN2_l(xn) + attn_{l+1} )
      ln_chain<1><<<2 * BDIM / 4, 256, 0, stream>>>(
          xn, hreg, ln2g + l * 512, ln2b + l * 512,
          ln1g + (l + 1) * 512, ln1b + (l + 1) * 512, xn);
    } else {
      // xn = LN2_2(xn)   (final x)
      ln_chain<0><<<2 * BDIM / 4, 256, 0, stream>>>(
          xn, nullptr, ln2g + l * 512, ln2b + l * 512, nullptr, nullptr, xn);
    }
  }

  // gen = xn @ opw^T + opb  (z=0 -> gen_text, z=1 -> gen_img) -> hreg
  gemm_8p<0, false, 512><<<dim3(64, 2, 2), 512, 0, stream>>>(
      xn, BS, op_bf, 262144, opb, 512, nullptr, 0, hreg, BS, 512);

  combine<<<(BDIM * 128 + 255) / 256, 256, 0, stream>>>(img, txt, hreg, hreg + BS,
                                                        pout, mt, rw, out);
}

// Round 15
// 819.074 us; speedup vs baseline: 1.0144x; 1.0144x over previous
//
#include <hip/hip_runtime.h>
#include <hip/hip_bf16.h>
#include <math.h>

#define BDIM 16384
#define HDIM 512

typedef __bf16 bf16;
typedef float f32x4 __attribute__((ext_vector_type(4)));
typedef __bf16 bf16x8 __attribute__((ext_vector_type(8)));
typedef __bf16 bf16x4 __attribute__((ext_vector_type(4)));

#define WAITV(N) asm volatile("s_waitcnt vmcnt(" #N ")" ::: "memory")

// ---------------------------------------------------------------- utilities

__device__ __forceinline__ void gload16(const bf16* g, bf16* l) {
  __builtin_amdgcn_global_load_lds((const __attribute__((address_space(1))) void*)g,
                                   (__attribute__((address_space(3))) void*)l, 16, 0, 0);
}

__device__ __forceinline__ float gelu_exact(float x) {
  return 0.5f * x * (1.0f + erff(x * 0.70710678118654752f));
}
__device__ __forceinline__ float gelu_fast2(float x) {
  float x3 = x * x * x;
  float e = exp2f(fmaf(-0.1029432f, x3, -2.3022082f * x));
  return x * __builtin_amdgcn_rcpf(1.f + e);
}

// ---------------------------------------------------------------- converts / prep

__global__ void cvt_f32_bf16(const float* __restrict__ src, bf16* __restrict__ dst, int n4) {
  int i = blockIdx.x * blockDim.x + threadIdx.x;
  if (i >= n4) return;
  f32x4 v = *(const f32x4*)(src + (size_t)i * 4);
  bf16x4 o;
  o[0] = (bf16)v[0]; o[1] = (bf16)v[1]; o[2] = (bf16)v[2]; o[3] = (bf16)v[3];
  *(bf16x4*)(dst + (size_t)i * 4) = o;
}

// cat[r] = [img[r] | txt[r]]  (16384 x 1024 bf16)
__global__ void cvt_cat(const float* __restrict__ img, const float* __restrict__ txt,
                        bf16* __restrict__ cat) {
  int i = blockIdx.x * 256 + threadIdx.x;       // 16384*128 groups of 8
  int r = i >> 7;
  int c = (i & 127) << 3;
  const float* s = (c < 512) ? (img + (size_t)r * 512 + c)
                             : (txt + (size_t)r * 512 + (c - 512));
  f32x4 v0 = *(const f32x4*)s;
  f32x4 v1 = *(const f32x4*)(s + 4);
  bf16x8 o;
#pragma unroll
  for (int j = 0; j < 4; ++j) { o[j] = (bf16)v0[j]; o[4 + j] = (bf16)v1[j]; }
  *(bf16x8*)(cat + (size_t)r * 1024 + c) = o;
}

// Wcat[0][n] = [ipw0[n] | Wc(il=0)[n]];  Wcat[1][n] = [Wc(il=3)[n] | ipw1[n]]
__global__ void cat_w(const bf16* __restrict__ ipw_bf, const bf16* __restrict__ Wc_bf,
                      bf16* __restrict__ Wcat) {
  int i = blockIdx.x * 256 + threadIdx.x;       // 2*512*128 groups of 8
  int g = i >> 16;
  int rem = i & 65535;
  int n = rem >> 7;
  int c = (rem & 127) << 3;
  const bf16* s;
  if (g == 0) s = (c < 512) ? (ipw_bf + (size_t)n * 512 + c)
                            : (Wc_bf + (size_t)n * 512 + (c - 512));
  else        s = (c < 512) ? (Wc_bf + (size_t)3 * 262144 + (size_t)n * 512 + c)
                            : (ipw_bf + 262144 + (size_t)n * 512 + (c - 512));
  *(bf16x8*)(Wcat + (size_t)g * 524288 + (size_t)n * 1024 + c) = *(const bf16x8*)s;
}

// bcat[g][n] = ipb[g][n] + bc[g*3+0][n]
__global__ void bcat_k(const float* __restrict__ ipb, const float* __restrict__ bc,
                       float* __restrict__ bcat) {
  int i = blockIdx.x * 256 + threadIdx.x;       // 1024
  int g = i >> 9, n = i & 511;
  bcat[i] = ipb[g * 512 + n] + bc[g * 1536 + n];
}

// wvT[il][k][m] = wv[il][m][k]; wv = rows 1024..1535 of qkv block il ([1536][512])
__global__ void cvt_wvT(const float* __restrict__ qkv, bf16* __restrict__ dst) {
  __shared__ float t[32][33];
  int il = blockIdx.z;
  int bm = blockIdx.x * 32;
  int bk = blockIdx.y * 32;
  const float* s = qkv + (size_t)il * 786432 + 524288;
  int tx = threadIdx.x & 31, ty = threadIdx.x >> 5;
#pragma unroll
  for (int j = 0; j < 4; ++j)
    t[ty * 4 + j][tx] = s[(size_t)(bm + ty * 4 + j) * 512 + bk + tx];
  __syncthreads();
  bf16* d = dst + (size_t)il * 262144;
#pragma unroll
  for (int j = 0; j < 4; ++j)
    d[(size_t)(bk + ty * 4 + j) * 512 + bm + tx] = (bf16)t[tx][ty * 4 + j];
}

__global__ void zfill(float* __restrict__ p, int n) {
  int i = blockIdx.x * 256 + threadIdx.x;
  if (i < n) p[i] = 0.f;
}

// bc[il][n] = sum_m ao[il][n][m] * bv[il][m] + aob[il][n]
__global__ void bias_combine(const float* __restrict__ aow, const float* __restrict__ qkvb,
                             const float* __restrict__ aob, float* __restrict__ bc) {
  int gid = blockIdx.x * 4 + (threadIdx.x >> 6);
  int il = gid >> 9;
  int lane = threadIdx.x & 63;
  const float* ar = aow + (size_t)gid * 512 + lane * 8;
  const float* bv = qkvb + il * 1536 + 1024 + lane * 8;
  float s = 0.f;
#pragma unroll
  for (int i = 0; i < 8; ++i) s += ar[i] * bv[i];
#pragma unroll
  for (int off = 32; off > 0; off >>= 1) s += __shfl_xor(s, off);
  if (lane == 0) bc[gid] = s + aob[gid];
}

// ---------------------------------------------------------------- gemm_8p (all big GEMMs)
// 256x256 tile, BK=64, 8 waves (2Mx4N), 128 KiB LDS: 2 bufs x 4 regions.
// 8-phase read-ahead schedule (r13/r14 verified ledger). lda = A row stride.
// FIN=0: C = act(A@W^T + bias [+X]) bf16.  FIN=1: final blend/select -> f32 out.

template<int ACT, bool RES, int K, int FIN>
__launch_bounds__(512, 1)
__global__ void gemm_8p(const bf16* __restrict__ A, long long Az, int lda,
                        const bf16* __restrict__ W, long long Wz,
                        const float* __restrict__ bias, long long bz,
                        const bf16* X, long long Xz,
                        bf16* C, long long Cz, int ldc,
                        const float* imgF, const float* txtF,
                        const float* prior, const int* mt,
                        const float* rwp, float* outF) {
  __shared__ bf16 lds[65536];   // 128 KiB
  const long long z = blockIdx.z;
  A += z * Az; W += z * Wz; bias += z * bz; C += z * Cz;
  if (RES) X += z * Xz;
  const int tid = threadIdx.x, lane = tid & 63, wid = tid >> 6;
  const int brow = blockIdx.x * 256, bcol = blockIdx.y * 256;
  const int wm = (wid >> 2) * 128;
  const int wn = (wid & 3) * 64;
  const int lr = lane & 15, kg = lane >> 4;
  const int ko = (kg ^ ((lr >> 1) & 3)) << 3;

  f32x4 acc[8][4] = {};

  const int sco = (((tid & 3) ^ ((tid >> 3) & 3)) << 3);
  const bf16* Ag = A + (size_t)(brow + (tid >> 2)) * lda + sco;
  const bf16* Wg = W + (size_t)(bcol + (tid >> 2)) * K + sco;
  const int nt = K / 64;

  auto STG = [&](const bf16* gbase, int kt, int kh, int dstE, int rstride) {
    int ck = kt < nt ? kt : nt - 1;   // dummy-clamp keeps vmcnt ledger uniform
    const bf16* s = gbase + (size_t)ck * 64 + (size_t)kh * 32;
    gload16(s, lds + dstE + wid * 512);
    gload16(s + (size_t)128 * rstride, lds + dstE + 4096 + wid * 512);
  };

  // prologue stages (ledger order): (0)A0,(0)B0,(0)A1,(0)B1,(1)A0,(1)B0
  STG(Ag, 0, 0, 0, lda);         STG(Wg, 0, 0, 16384, K);
  STG(Ag, 0, 1, 8192, lda);      STG(Wg, 0, 1, 24576, K);
  STG(Ag, 1, 0, 32768, lda);     STG(Wg, 1, 0, 49152, K);

  bf16x8 a[8], b01[2], b23[2];

#define RD_A(BASE)                                                             \
  { _Pragma("unroll") for (int m = 0; m < 8; ++m)                              \
      a[m] = *(const bf16x8*)(lds + (BASE) + ((wm + m * 16 + lr) << 5) + ko); }
#define RD_B01(BASE)                                                           \
  { b01[0] = *(const bf16x8*)(lds + (BASE) + ((wn + lr) << 5) + ko);           \
    b01[1] = *(const bf16x8*)(lds + (BASE) + ((wn + 16 + lr) << 5) + ko); }
#define RD_B23(BASE)                                                           \
  { b23[0] = *(const bf16x8*)(lds + (BASE) + ((wn + 32 + lr) << 5) + ko);      \
    b23[1] = *(const bf16x8*)(lds + (BASE) + ((wn + 48 + lr) << 5) + ko); }
#define MM(N0, BB)                                                             \
  { __builtin_amdgcn_s_setprio(1);                                             \
    _Pragma("unroll") for (int m = 0; m < 8; ++m) {                            \
      acc[m][N0]     = __builtin_amdgcn_mfma_f32_16x16x32_bf16(BB[0], a[m], acc[m][N0], 0, 0, 0);     \
      acc[m][N0 + 1] = __builtin_amdgcn_mfma_f32_16x16x32_bf16(BB[1], a[m], acc[m][N0 + 1], 0, 0, 0); } \
    __builtin_amdgcn_s_setprio(0); }
#define BARW                                                                   \
  WAITV(6); __builtin_amdgcn_s_barrier(); asm volatile("" ::: "memory");
#define ENDP                                                                   \
  asm volatile("" ::: "memory"); __builtin_amdgcn_s_barrier();

  BARW
  RD_A(0) RD_B01(16384)

  const int niter = nt / 2;
  for (int i = 0; i < niter; ++i) {
    const int t = 2 * i;
    STG(Ag, t + 1, 1, 40960, lda);
    BARW  MM(0, b01)  RD_B23(16384)                      ENDP
    STG(Wg, t + 1, 1, 57344, K);
    BARW  MM(2, b23)  RD_A(8192) RD_B01(24576)           ENDP
    STG(Ag, t + 2, 0, 0, lda);
    BARW  MM(0, b01)  RD_B23(24576)                      ENDP
    STG(Wg, t + 2, 0, 16384, K);
    BARW  MM(2, b23)  RD_A(32768) RD_B01(49152)          ENDP
    STG(Ag, t + 2, 1, 8192, lda);
    BARW  MM(0, b01)  RD_B23(49152)                      ENDP
    STG(Wg, t + 2, 1, 24576, K);
    BARW  MM(2, b23)  RD_A(40960) RD_B01(57344)          ENDP
    STG(Ag, t + 3, 0, 32768, lda);
    BARW  MM(0, b01)  RD_B23(57344)                      ENDP
    STG(Wg, t + 3, 0, 49152, K);
    BARW  MM(2, b23)  RD_A(0) RD_B01(16384)              ENDP
  }
#undef RD_A
#undef RD_B01
#undef RD_B23
#undef MM
#undef BARW
#undef ENDP

  // epilogue (swapped D): row = brow+wm+m*16+lr; cols = bcol+wn+n*16+kg*4 .. +3
  f32x4 bv4[4];
#pragma unroll
  for (int n = 0; n < 4; ++n)
    bv4[n] = *(const f32x4*)(bias + bcol + wn + n * 16 + kg * 4);

  if constexpr (FIN == 1) {
    // final: gen = acc+bias; blend/select with mt -> f32 out
    float r = rwp[z];
    const float* basep = z ? imgF : txtF;
    const float* pr = prior + (z ? 0 : 512);
    float* op2 = outF + (z ? (size_t)0 : (size_t)BDIM * HDIM);
    const int want = z ? 2 : 1;
#pragma unroll
    for (int m = 0; m < 8; ++m) {
      int row = brow + wm + m * 16 + lr;
      int msel = mt[row];
#pragma unroll
      for (int n = 0; n < 4; ++n) {
        int col = bcol + wn + n * 16 + kg * 4;
        f32x4 base4 = *(const f32x4*)(basep + (size_t)row * 512 + col);
        f32x4 o;
#pragma unroll
        for (int j = 0; j < 4; ++j) {
          float g = acc[m][n][j] + bv4[n][j];
          float ov = base4[j];
          if (msel == want) ov = r * base4[j] + (1.f - r) * g;
          else if (msel == 3) ov = pr[col + j];
          o[j] = ov;
        }
        *(f32x4*)(op2 + (size_t)row * 512 + col) = o;
      }
    }
    return;
  }

#pragma unroll
  for (int m = 0; m < 8; ++m) {
    int row = brow + wm + m * 16 + lr;
#pragma unroll
    for (int n = 0; n < 4; ++n) {
      int col = bcol + wn + n * 16 + kg * 4;
      f32x4 v;
#pragma unroll
      for (int j = 0; j < 4; ++j) {
        float t2 = acc[m][n][j] + bv4[n][j];
        if (ACT == 1) t2 = gelu_fast2(t2);
        v[j] = t2;
      }
      if (RES) {
        bf16x4 xv = *(const bf16x4*)(X + (size_t)row * 512 + col);
#pragma unroll
        for (int j = 0; j < 4; ++j) v[j] += (float)xv[j];
      }
      bf16x4 o;
#pragma unroll
      for (int j = 0; j < 4; ++j) o[j] = (bf16)v[j];
      *(bf16x4*)(C + (size_t)row * ldc + col) = o;
    }
  }
}

// ---------------------------------------------------------------- ln_chain
// MODE 0: O = LN_A(Y);  MODE 1: O = LN_B( LN_A(Y) + R )

template<int MODE>
__global__ void ln_chain(const bf16* __restrict__ Y, const bf16* __restrict__ R,
                         const float* __restrict__ gA, const float* __restrict__ bA,
                         const float* __restrict__ gB, const float* __restrict__ bB,
                         bf16* __restrict__ O) {
  int lane = threadIdx.x & 63;
  int row = blockIdx.x * 4 + (threadIdx.x >> 6);
  int gen = row >> 14;
  size_t base = (size_t)row * HDIM + lane * 8;
  bf16x8 yv = *(const bf16x8*)(Y + base);
  float v[8], s = 0.f, q = 0.f;
#pragma unroll
  for (int i = 0; i < 8; ++i) { v[i] = (float)yv[i]; s += v[i]; q += v[i] * v[i]; }
#pragma unroll
  for (int off = 32; off > 0; off >>= 1) { s += __shfl_xor(s, off); q += __shfl_xor(q, off); }
  float mean = s * (1.f / HDIM);
  float rstd = rsqrtf(q * (1.f / HDIM) - mean * mean + 1e-5f);
  const float* gAp = gA + gen * 1536 + lane * 8;
  const float* bAp = bA + gen * 1536 + lane * 8;
  if (MODE == 0) {
    bf16x8 o;
#pragma unroll
    for (int i = 0; i < 8; ++i) o[i] = (bf16)((v[i] - mean) * rstd * gAp[i] + bAp[i]);
    *(bf16x8*)(O + base) = o;
    return;
  }
  bf16x8 rv = *(const bf16x8*)(R + base);
  float u[8]; s = 0.f; q = 0.f;
#pragma unroll
  for (int i = 0; i < 8; ++i) {
    u[i] = (v[i] - mean) * rstd * gAp[i] + bAp[i] + (float)rv[i];
    s += u[i]; q += u[i] * u[i];
  }
#pragma unroll
  for (int off = 32; off > 0; off >>= 1) { s += __shfl_xor(s, off); q += __shfl_xor(q, off); }
  float m2 = s * (1.f / HDIM);
  float r2 = rsqrtf(q * (1.f / HDIM) - m2 * m2 + 1e-5f);
  const float* gBp = gB + gen * 1536 + lane * 8;
  const float* bBp = bB + gen * 1536 + lane * 8;
  bf16x8 o;
#pragma unroll
  for (int i = 0; i < 8; ++i) o[i] = (bf16)((u[i] - m2) * r2 * gBp[i] + bBp[i]);
  *(bf16x8*)(O + base) = o;
}

// ---------------------------------------------------------------- GEMM 128x128 (tiny: Wc)

__launch_bounds__(256)
__global__ void gemm128(const bf16* __restrict__ A, long long Az, int lda,
                        const bf16* __restrict__ W, long long Wz,
                        const float* __restrict__ bias, long long bz,
                        bf16* __restrict__ C, long long Cz, int ldc, int K) {
  __shared__ bf16 As[128 * 64];
  __shared__ bf16 Bs[128 * 64];
  const long long z = blockIdx.z;
  A += z * Az; W += z * Wz; bias += z * bz; C += z * Cz;
  const int tid = threadIdx.x;
  const int lane = tid & 63;
  const int wid = tid >> 6;
  const int brow = blockIdx.x * 128;
  const int bcol = blockIdx.y * 128;
  const int wr = (wid >> 1) * 64;
  const int wc = (wid & 1) * 64;
  const int lr = lane & 15;
  const int kg = lane >> 4;
  f32x4 acc[4][4] = {};
  const bf16* Abase = A + (size_t)(brow + (tid >> 3)) * lda + ((tid & 7) << 3);
  const bf16* Wbase = W + (size_t)(bcol + (tid >> 3)) * K + ((tid & 7) << 3);
  bf16* AsDst = As + wid * 512;
  bf16* BsDst = Bs + wid * 512;
  for (int k0 = 0; k0 < K; k0 += 64) {
#pragma unroll
    for (int j = 0; j < 4; ++j) {
      gload16(Abase + (size_t)j * 32 * lda + k0, AsDst + j * 2048);
      gload16(Wbase + (size_t)j * 32 * K + k0, BsDst + j * 2048);
    }
    __syncthreads();
#pragma unroll
    for (int kk = 0; kk < 64; kk += 32) {
      bf16x8 a[4], bq[4];
#pragma unroll
      for (int m = 0; m < 4; ++m)
        a[m] = *(const bf16x8*)(As + (wr + m * 16 + lr) * 64 + kk + kg * 8);
#pragma unroll
      for (int n = 0; n < 4; ++n)
        bq[n] = *(const bf16x8*)(Bs + (wc + n * 16 + lr) * 64 + kk + kg * 8);
#pragma unroll
      for (int m = 0; m < 4; ++m)
#pragma unroll
        for (int n = 0; n < 4; ++n)
          acc[m][n] = __builtin_amdgcn_mfma_f32_16x16x32_bf16(a[m], bq[n], acc[m][n], 0, 0, 0);
    }
    __syncthreads();
  }
  float bv[4];
#pragma unroll
  for (int n = 0; n < 4; ++n) bv[n] = bias[bcol + wc + n * 16 + lr];
#pragma unroll
  for (int m = 0; m < 4; ++m) {
    int row = brow + wr + m * 16 + kg * 4;
#pragma unroll
    for (int n = 0; n < 4; ++n) {
      int col = bcol + wc + n * 16 + lr;
#pragma unroll
      for (int j = 0; j < 4; ++j)
        C[(size_t)(row + j) * ldc + col] = (bf16)(acc[m][n][j] + bv[n]);
    }
  }
}

// ---------------------------------------------------------------- prior MLP (tiny)

__global__ void prior_fc1(const float* __restrict__ emb, const float* __restrict__ w1,
                          const float* __restrict__ b1, float* __restrict__ h) {
  int j = blockIdx.x * 4 + (threadIdx.x >> 6);
  int lane = threadIdx.x & 63;
  const float* wr = w1 + (size_t)j * 512 + lane * 8;
  const float* e = emb + lane * 8;
  float s = 0.f;
#pragma unroll
  for (int i = 0; i < 8; ++i) s += e[i] * wr[i];
#pragma unroll
  for (int off = 32; off > 0; off >>= 1) s += __shfl_xor(s, off);
  if (lane == 0) h[j] = gelu_exact(s + b1[j]);
}

__global__ void prior_fc2(const float* __restrict__ h, const float* __restrict__ w2,
                          const float* __restrict__ b2, float* __restrict__ p) {
  int j = blockIdx.x * 4 + (threadIdx.x >> 6);
  int lane = threadIdx.x & 63;
  const float* wr = w2 + (size_t)j * 1024 + lane * 16;
  const float* e = h + lane * 16;
  float s = 0.f;
#pragma unroll
  for (int i = 0; i < 16; ++i) s += e[i] * wr[i];
#pragma unroll
  for (int off = 32; off > 0; off >>= 1) s += __shfl_xor(s, off);
  if (lane == 0) p[j] = s + b2[j];
}

// ---------------------------------------------------------------- launch

extern "C" void kernel_launch(void* const* d_in, const int* in_sizes, int n_in,
                              void* d_out, int out_size, void* d_ws, size_t ws_size,
                              hipStream_t stream) {
  const float* img  = (const float*)d_in[0];
  const float* txt  = (const float*)d_in[1];
  const float* ipw  = (const float*)d_in[2];
  const float* ipb  = (const float*)d_in[3];
  const float* qkvw = (const float*)d_in[4];
  const float* qkvb = (const float*)d_in[5];
  const float* aow  = (const float*)d_in[6];
  const float* aob  = (const float*)d_in[7];
  const float* ln1g = (const float*)d_in[8];
  const float* ln1b = (const float*)d_in[9];
  const float* ln2g = (const float*)d_in[10];
  const float* ln2b = (const float*)d_in[11];
  const float* f1w  = (const float*)d_in[12];
  const float* f1b  = (const float*)d_in[13];
  const float* f2w  = (const float*)d_in[14];
  const float* f2b  = (const float*)d_in[15];
  const float* opw  = (const float*)d_in[16];
  const float* opb  = (const float*)d_in[17];
  const float* rw   = (const float*)d_in[18];
  const float* pw1  = (const float*)d_in[19];
  const float* pb1  = (const float*)d_in[20];
  const float* pw2  = (const float*)d_in[21];
  const float* pb2  = (const float*)d_in[22];
  const float* pemb = (const float*)d_in[23];
  const int*   mt   = (const int*)d_in[24];
  float* out = (float*)d_out;

  const size_t B = BDIM;
  char* ws = (char*)d_ws;
  size_t off = 0;
  auto alloc = [&](size_t bytes) -> char* {
    char* p = ws + off;
    off += (bytes + 255) & ~(size_t)255;
    return p;
  };
  bf16* cat    = (bf16*)alloc((size_t)B * 1024 * 2);       // [img|txt] rows
  bf16* ipw_bf = (bf16*)alloc((size_t)2 * 262144 * 2);
  bf16* wvT_bf = (bf16*)alloc((size_t)6 * 262144 * 2);
  bf16* ao_bf  = (bf16*)alloc((size_t)6 * 262144 * 2);
  bf16* f1_bf  = (bf16*)alloc((size_t)6 * 1048576 * 2);
  bf16* f2_bf  = (bf16*)alloc((size_t)6 * 1048576 * 2);
  bf16* op_bf  = (bf16*)alloc((size_t)2 * 262144 * 2);
  bf16* Wc_bf  = (bf16*)alloc((size_t)6 * 262144 * 2);
  bf16* Wcat   = (bf16*)alloc((size_t)2 * 524288 * 2);
  float* bc    = (float*)alloc(6 * 512 * 4);
  float* bcat  = (float*)alloc(1024 * 4);
  float* zeros = (float*)alloc(512 * 4);
  float* ph    = (float*)alloc(1024 * 4);
  float* pout  = (float*)alloc(1024 * 4);
  bf16* xn     = (bf16*)alloc(2 * B * 512 * 2);
  bf16* hreg   = (bf16*)alloc((size_t)B * 2048 * 2);   // gen1 h / attn buf
  bf16* h0     = (bf16*)d_out;                          // gen0 h (dead before final op)
  const long long HZ = (long long)(hreg - h0);

  auto cvt = [&](const float* s, bf16* d, size_t n) {
    int n4 = (int)(n / 4);
    cvt_f32_bf16<<<(n4 + 255) / 256, 256, 0, stream>>>(s, d, n4);
  };
  cvt_cat<<<8192, 256, 0, stream>>>(img, txt, cat);
  cvt(ipw, ipw_bf, 2 * 262144);
  cvt(aow, ao_bf, 6 * 262144);
  cvt(f1w, f1_bf, 6 * 1048576);
  cvt(f2w, f2_bf, 6 * 1048576);
  cvt(opw, op_bf, 2 * 262144);
  cvt_wvT<<<dim3(16, 16, 6), 256, 0, stream>>>(qkvw, wvT_bf);
  zfill<<<2, 256, 0, stream>>>(zeros, 512);
  bias_combine<<<768, 256, 0, stream>>>(aow, qkvb, aob, bc);
  gemm128<<<dim3(4, 4, 6), 256, 0, stream>>>(ao_bf, 262144, 512, wvT_bf, 262144,
                                             zeros, 0, Wc_bf, 262144, 512, 512);
  cat_w<<<512, 256, 0, stream>>>(ipw_bf, Wc_bf, Wcat);
  bcat_k<<<4, 256, 0, stream>>>(ipb, bc, bcat);
  prior_fc1<<<256, 256, 0, stream>>>(pemb, pw1, pb1, ph);
  prior_fc2<<<256, 256, 0, stream>>>(ph, pw2, pb2, pout);

  const long long BS = (long long)B * 512;

  // attn_l (l>=1): tgt slice of cat; z=0 -> txt (cat+512), z=1 -> img (cat)
  auto attn = [&](int l) {
    gemm_8p<0, false, 512, 0><<<dim3(64, 2, 2), 512, 0, stream>>>(
        cat + 512, -512, 1024, Wc_bf + (size_t)l * 262144, 786432,
        bc + l * 512, 1536, nullptr, 0, hreg, BS, 512,
        nullptr, nullptr, nullptr, nullptr, nullptr, nullptr);
  };

  // xn = LN1_0( cat @ Wcat^T + bcat )   (merged ip + attn0, K=1024)
  gemm_8p<0, false, 1024, 0><<<dim3(64, 2, 2), 512, 0, stream>>>(
      cat, 0, 1024, Wcat, 524288, bcat, 512, nullptr, 0, xn, BS, 512,
      nullptr, nullptr, nullptr, nullptr, nullptr, nullptr);
  ln_chain<0><<<2 * BDIM / 4, 256, 0, stream>>>(xn, nullptr, ln1g, ln1b,
                                                nullptr, nullptr, xn);

  for (int l = 0; l < 3; ++l) {
    // h = gelu(xn @ f1^T + b1)   (z-batched: gen0 h in d_out, gen1 in hreg)
    gemm_8p<1, false, 512, 0><<<dim3(64, 8, 2), 512, 0, stream>>>(
        xn, BS, 512, f1_bf + (size_t)l * 1048576, 3145728,
        f1b + l * 2048, 6144, nullptr, 0, h0, HZ, 2048,
        nullptr, nullptr, nullptr, nullptr, nullptr, nullptr);
    // xn = xn + h @ f2^T + b2   (z-batched, in place)
    gemm_8p<0, true, 2048, 0><<<dim3(64, 2, 2), 512, 0, stream>>>(
        h0, HZ, 2048, f2_bf + (size_t)l * 1048576, 3145728,
        f2b + l * 512, 1536, xn, BS, xn, BS, 512,
        nullptr, nullptr, nullptr, nullptr, nullptr, nullptr);
    if (l < 2) {
      attn(l + 1);   // h dead now; hreg reused as attn buffer
      ln_chain<1><<<2 * BDIM / 4, 256, 0, stream>>>(
          xn, hreg, ln2g + l * 512, ln2b + l * 512,
          ln1g + (l + 1) * 512, ln1b + (l + 1) * 512, xn);
    } else {
      ln_chain<0><<<2 * BDIM / 4, 256, 0, stream>>>(
          xn, nullptr, ln2g + l * 512, ln2b + l * 512, nullptr, nullptr, xn);
    }
  }

  // final: gen = xn @ opw^T + opb; blend/select -> f32 out (fused combine)
  gemm_8p<0, false, 512, 1><<<dim3(64, 2, 2), 512, 0, stream>>>(
      xn, BS, 512, op_bf, 262144, opb, 512, nullptr, 0, hreg, BS, 512,
      img, txt, pout, mt, rw, out);
}